// Round 1
// baseline (946.005 us; speedup 1.0000x reference)
//
#include <hip/hip_runtime.h>
#include <math.h>

#define LSEQ 768
#define CS   384
#define CZ   128
#define NH   12
#define DH   32
#define OUTD 2208
#define LL2  (LSEQ*LSEQ)

__device__ __forceinline__ float waveSum(float v){
#pragma unroll
  for (int o = 32; o > 0; o >>= 1) v += __shfl_down(v, o, 64);
  return v;
}
__device__ __forceinline__ float waveMax(float v){
#pragma unroll
  for (int o = 32; o > 0; o >>= 1) v = fmaxf(v, __shfl_down(v, o, 64));
  return v;
}

// ---------------- LayerNorm ----------------
__global__ __launch_bounds__(128) void k_layernorm(
    const float* __restrict__ x, const float* __restrict__ g,
    const float* __restrict__ b, float* __restrict__ s){
  int i = blockIdx.x, t = threadIdx.x;
  const float* row = x + (size_t)i*CS;
  float v0 = row[t], v1 = row[t+128], v2 = row[t+256];
  float sum = v0+v1+v2;
  float sq  = v0*v0+v1*v1+v2*v2;
  float ws1 = waveSum(sum), ws2 = waveSum(sq);
  __shared__ float red[4];
  int w = t>>6, lane = t&63;
  if (lane == 0){ red[w] = ws1; red[w+2] = ws2; }
  __syncthreads();
  float mu   = (red[0]+red[1]) * (1.f/CS);
  float var  = (red[2]+red[3]) * (1.f/CS) - mu*mu;
  float rstd = rsqrtf(var + 1e-5f);
  float* o = s + (size_t)i*CS;
  o[t]     = (v0-mu)*rstd*g[t]     + b[t];
  o[t+128] = (v1-mu)*rstd*g[t+128] + b[t+128];
  o[t+256] = (v2-mu)*rstd*g[t+256] + b[t+256];
}

// ---------------- generic tiled GEMM (64x64, BK=16), optional split-K ----------------
__global__ __launch_bounds__(256) void k_gemm(
    const float* __restrict__ A, const float* __restrict__ B,
    const float* __restrict__ bias, float* __restrict__ C,
    int M, int N, int K, int kChunk){
  __shared__ float As[16][65];
  __shared__ float Bs[16][65];
  int j0 = blockIdx.x*64, i0 = blockIdx.y*64;
  int kBeg = blockIdx.z * kChunk;
  int t = threadIdx.x, tx = t & 15, ty = t >> 4;
  int arow = t >> 2, ak = (t & 3) * 4;
  int brow = t >> 4, bcol = (t & 15) * 4;
  float acc[4][4] = {};
  for (int kb = kBeg; kb < kBeg + kChunk; kb += 16){
    float4 av = *(const float4*)(A + (size_t)(i0+arow)*K + kb + ak);
    As[ak+0][arow]=av.x; As[ak+1][arow]=av.y; As[ak+2][arow]=av.z; As[ak+3][arow]=av.w;
    float4 bv = make_float4(0.f,0.f,0.f,0.f);
    if (j0 + bcol < N) bv = *(const float4*)(B + (size_t)(kb+brow)*N + j0 + bcol);
    Bs[brow][bcol+0]=bv.x; Bs[brow][bcol+1]=bv.y; Bs[brow][bcol+2]=bv.z; Bs[brow][bcol+3]=bv.w;
    __syncthreads();
#pragma unroll
    for (int kk = 0; kk < 16; ++kk){
      float a0=As[kk][ty*4+0],a1=As[kk][ty*4+1],a2=As[kk][ty*4+2],a3=As[kk][ty*4+3];
      float b0=Bs[kk][tx*4+0],b1=Bs[kk][tx*4+1],b2=Bs[kk][tx*4+2],b3=Bs[kk][tx*4+3];
      acc[0][0]+=a0*b0; acc[0][1]+=a0*b1; acc[0][2]+=a0*b2; acc[0][3]+=a0*b3;
      acc[1][0]+=a1*b0; acc[1][1]+=a1*b1; acc[1][2]+=a1*b2; acc[1][3]+=a1*b3;
      acc[2][0]+=a2*b0; acc[2][1]+=a2*b1; acc[2][2]+=a2*b2; acc[2][3]+=a2*b3;
      acc[3][0]+=a3*b0; acc[3][1]+=a3*b1; acc[3][2]+=a3*b2; acc[3][3]+=a3*b3;
    }
    __syncthreads();
  }
  size_t zoff = (size_t)blockIdx.z * M * N;
  bool noSplit = (gridDim.z == 1);
#pragma unroll
  for (int r = 0; r < 4; ++r){
    int i = i0 + ty*4 + r;
#pragma unroll
    for (int c = 0; c < 4; ++c){
      int j = j0 + tx*4 + c;
      if (j < N){
        float v = acc[r][c];
        if (noSplit && bias) v += bias[j];
        C[zoff + (size_t)i*N + j] = v;
      }
    }
  }
}

// ---------------- apply frames in-place: p <- R p + t ----------------
__global__ void k_frames(float* __restrict__ pts, const float* __restrict__ rots,
                         const float* __restrict__ trans, int npr){
  int idx = blockIdx.x*256 + threadIdx.x;
  if (idx >= LSEQ*npr) return;
  int i = idx / npr;
  float* p = pts + (size_t)idx*3;
  const float* R  = rots + i*9;
  const float* tr = trans + i*3;
  float x=p[0], y=p[1], z=p[2];
  p[0] = R[0]*x + R[1]*y + R[2]*z + tr[0];
  p[1] = R[3]*x + R[4]*y + R[5]*z + tr[1];
  p[2] = R[6]*x + R[7]*y + R[8]*z + tr[2];
}

// ---------------- build Bmat[h][j][56] = [v(32) | v_g(24)] ----------------
__global__ void k_bmat(const float* __restrict__ v, const float* __restrict__ vg,
                       float* __restrict__ bmat){
  int idx = blockIdx.x*256 + threadIdx.x;
  if (idx >= NH*LSEQ*56) return;
  int h = idx/(LSEQ*56); int r = idx%(LSEQ*56); int j = r/56; int n = r%56;
  float val = (n < 32) ? v[(size_t)j*CS + h*32 + n]
                       : vg[(size_t)j*288 + h*24 + (n-32)];
  bmat[idx] = val;
}

// ---------------- qk logits: logits[h][i][j] = q_ih . k_jh / sqrt(32) ----------------
__global__ __launch_bounds__(256) void k_qk(
    const float* __restrict__ q, const float* __restrict__ k,
    float* __restrict__ logits){
  int h = blockIdx.z, i0 = blockIdx.y*64, j0 = blockIdx.x*64;
  __shared__ float Qs[64][33], Ks[64][33];
  int t = threadIdx.x;
  for (int idx = t; idx < 512; idx += 256){
    int row = idx >> 3, d4 = (idx & 7)*4;
    float4 qv = *(const float4*)(q + (size_t)(i0+row)*CS + h*DH + d4);
    Qs[row][d4]=qv.x; Qs[row][d4+1]=qv.y; Qs[row][d4+2]=qv.z; Qs[row][d4+3]=qv.w;
    float4 kv = *(const float4*)(k + (size_t)(j0+row)*CS + h*DH + d4);
    Ks[row][d4]=kv.x; Ks[row][d4+1]=kv.y; Ks[row][d4+2]=kv.z; Ks[row][d4+3]=kv.w;
  }
  __syncthreads();
  int tx = t & 15, ty = t >> 4;
  float acc[4][4] = {};
#pragma unroll
  for (int d = 0; d < 32; ++d){
    float a[4], b[4];
#pragma unroll
    for (int r=0;r<4;++r) a[r] = Qs[ty*4+r][d];
#pragma unroll
    for (int c=0;c<4;++c) b[c] = Ks[tx*4+c][d];
#pragma unroll
    for (int r=0;r<4;++r)
#pragma unroll
      for (int c=0;c<4;++c) acc[r][c] += a[r]*b[c];
  }
  const float sc = 0.17677669529663687f; // 1/sqrt(32)
#pragma unroll
  for (int r=0;r<4;++r)
#pragma unroll
    for (int c=0;c<4;++c)
      logits[((size_t)h*LSEQ + i0+ty*4+r)*LSEQ + j0 + tx*4+c] = acc[r][c]*sc;
}

// ---------------- point-distance term: logits -= 0.5*softplus(hw)*dist ----------------
__global__ __launch_bounds__(256) void k_dist(
    const float* __restrict__ qg, const float* __restrict__ kg,
    const float* __restrict__ hw, float* __restrict__ logits){
  int i = blockIdx.x, j0 = blockIdx.y*32, t = threadIdx.x;
  __shared__ float kT[32][145];
  __shared__ float qT[144];
  __shared__ float wc[12];
  for (int idx = t; idx < 1152; idx += 256){
    int r = idx/36, c4 = (idx%36)*4;
    const float* src = kg + (size_t)(j0+r)*144 + c4;
    kT[r][c4]=src[0]; kT[r][c4+1]=src[1]; kT[r][c4+2]=src[2]; kT[r][c4+3]=src[3];
  }
  if (t < 144) qT[t] = qg[(size_t)i*144 + t];
  if (t < 12)  wc[t] = log1pf(expf(hw[t]));
  __syncthreads();
  for (int task = t; task < 384; task += 256){
    int h = task >> 5, j = task & 31;
    float d = 0.f;
#pragma unroll
    for (int p = 0; p < 4; ++p){
      float dx = qT[h*12+p*3+0] - kT[j][h*12+p*3+0];
      float dy = qT[h*12+p*3+1] - kT[j][h*12+p*3+1];
      float dz = qT[h*12+p*3+2] - kT[j][h*12+p*3+2];
      d += dx*dx + dy*dy + dz*dz;
    }
    size_t off = ((size_t)h*LSEQ + i)*LSEQ + j0 + j;
    logits[off] -= 0.5f * wc[h] * d;
  }
}

// ---------------- pair bias: logits[h][row] += pair[row,:] . Wpb[:,h] ----------------
__global__ __launch_bounds__(256) void k_pairbias(
    const float* __restrict__ pair, const float* __restrict__ Wpb,
    float* __restrict__ logits){
  __shared__ float w4[4][1544];  // 4 offset copies -> 4 broadcast addrs land in 4 banks
  int t = threadIdx.x;
  for (int idx = t; idx < 1536; idx += 256){
    float wv = Wpb[idx];
    w4[0][idx]=wv; w4[1][idx]=wv; w4[2][idx]=wv; w4[3][idx]=wv;
  }
  __syncthreads();
  int rowq = t >> 2, cseg = t & 3;
  size_t row0 = (size_t)blockIdx.x * 256 + (size_t)rowq*4;
  const float* w = w4[cseg];
  float acc[4][12];
#pragma unroll
  for (int r=0;r<4;++r)
#pragma unroll
    for (int h=0;h<12;++h) acc[r][h]=0.f;
  const float* pbase = pair + row0*CZ + cseg*32;
  for (int c4 = 0; c4 < 8; ++c4){
    float pr[4][4];
#pragma unroll
    for (int r = 0; r < 4; ++r){
      float4 vv = *(const float4*)(pbase + (size_t)r*CZ + c4*4);
      pr[r][0]=vv.x; pr[r][1]=vv.y; pr[r][2]=vv.z; pr[r][3]=vv.w;
    }
    int cb = (cseg*32 + c4*4)*12;
#pragma unroll
    for (int cc = 0; cc < 4; ++cc){
#pragma unroll
      for (int h = 0; h < 12; ++h){
        float wv = w[cb + cc*12 + h];
        acc[0][h] += pr[0][cc]*wv;
        acc[1][h] += pr[1][cc]*wv;
        acc[2][h] += pr[2][cc]*wv;
        acc[3][h] += pr[3][cc]*wv;
      }
    }
  }
  // reduce across the 4 c-segments (lanes t^1, t^2 share rowq)
#pragma unroll
  for (int r=0;r<4;++r)
#pragma unroll
    for (int h=0;h<12;++h){
      float v = acc[r][h];
      v += __shfl_xor(v, 1, 64);
      v += __shfl_xor(v, 2, 64);
      acc[r][h] = v;
    }
  size_t myrow = row0 + cseg;  // lane cseg writes row r==cseg
#pragma unroll
  for (int h=0;h<12;++h){
    float v = acc[0][h];
    if (cseg==1) v = acc[1][h];
    if (cseg==2) v = acc[2][h];
    if (cseg==3) v = acc[3][h];
    logits[(size_t)h*LL2 + myrow] += v;
  }
}

// ---------------- row softmax over j ----------------
__global__ __launch_bounds__(256) void k_softmax(float* __restrict__ logits){
  size_t base = (size_t)blockIdx.x * LSEQ;
  int t = threadIdx.x;
  float x0 = logits[base+t], x1 = logits[base+t+256], x2 = logits[base+t+512];
  __shared__ float redm[4], reds[4];
  float m = fmaxf(x0, fmaxf(x1, x2));
  m = waveMax(m);
  int w = t>>6, lane = t&63;
  if (lane==0) redm[w] = m;
  __syncthreads();
  m = fmaxf(fmaxf(redm[0],redm[1]), fmaxf(redm[2],redm[3]));
  float e0 = expf(x0-m), e1 = expf(x1-m), e2 = expf(x2-m);
  float sm = waveSum(e0+e1+e2);
  if (lane==0) reds[w] = sm;
  __syncthreads();
  float inv = 1.f/(reds[0]+reds[1]+reds[2]+reds[3]);
  logits[base+t]     = e0*inv;
  logits[base+t+256] = e1*inv;
  logits[base+t+512] = e2*inv;
}

// ---------------- attn @ [v | v_g] with scatter into cat ----------------
__global__ __launch_bounds__(256) void k_pv(
    const float* __restrict__ attn, const float* __restrict__ bmat,
    float* __restrict__ cat){
  int h = blockIdx.y, i0 = blockIdx.x*64;
  __shared__ float As[32][65], Bs[32][65];
  int t = threadIdx.x, tx = t & 15, ty = t >> 4;
  float acc[4][4] = {};
  for (int kb = 0; kb < LSEQ; kb += 32){
    for (int idx = t; idx < 512; idx += 256){
      int row = idx >> 3, k4 = (idx & 7)*4;
      float4 av = *(const float4*)(attn + ((size_t)h*LSEQ + i0 + row)*LSEQ + kb + k4);
      As[k4+0][row]=av.x; As[k4+1][row]=av.y; As[k4+2][row]=av.z; As[k4+3][row]=av.w;
    }
    for (int idx = t; idx < 32*56; idx += 256){
      int kk = idx/56, n = idx%56;
      Bs[kk][n] = bmat[((size_t)h*LSEQ + kb + kk)*56 + n];
    }
    __syncthreads();
#pragma unroll
    for (int kk = 0; kk < 32; ++kk){
      float a[4], b[4];
#pragma unroll
      for (int r=0;r<4;++r) a[r] = As[kk][ty*4+r];
#pragma unroll
      for (int c=0;c<4;++c) b[c] = Bs[kk][tx*4+c];
#pragma unroll
      for (int r=0;r<4;++r)
#pragma unroll
        for (int c=0;c<4;++c) acc[r][c] += a[r]*b[c];
    }
    __syncthreads();
  }
#pragma unroll
  for (int r=0;r<4;++r){
    int i = i0 + ty*4 + r;
#pragma unroll
    for (int c=0;c<4;++c){
      int n = tx*4 + c;
      float val = acc[r][c];
      if (n < 32)      cat[(size_t)i*OUTD + h*32 + n] = val;
      else if (n < 56) cat[(size_t)i*OUTD + 384 + h*24 + (n-32)] = val;
    }
  }
}

// ---------------- rotate output points back to local frame (in cat, in-place) ----------------
__global__ void k_outpts(const float* __restrict__ rots, const float* __restrict__ trans,
                         float* __restrict__ cat){
  int idx = blockIdx.x*256 + threadIdx.x;
  if (idx >= LSEQ*96) return;
  int i = idx/96, n = idx%96;
  float* p = cat + (size_t)i*OUTD + 384 + n*3;
  const float* R  = rots + i*9;
  const float* tr = trans + i*3;
  float x = p[0]-tr[0], y = p[1]-tr[1], z = p[2]-tr[2];
  p[0] = R[0]*x + R[3]*y + R[6]*z;
  p[1] = R[1]*x + R[4]*y + R[7]*z;
  p[2] = R[2]*x + R[5]*y + R[8]*z;
}

// ---------------- out_pair[i,h,c] = sum_j attn[h,i,j]*pair[i,j,c] ----------------
__global__ __launch_bounds__(256) void k_outpair(
    const float* __restrict__ attn, const float* __restrict__ pair,
    float* __restrict__ cat){
  int i = blockIdx.x, t = threadIdx.x;
  __shared__ __align__(16) float aT[NH*LSEQ];   // 36.9 KB
  __shared__ __align__(16) float prT[8*CZ];     // 4 KB
  for (int idx4 = t; idx4 < NH*LSEQ/4; idx4 += 256){
    ((float4*)aT)[idx4] = *(const float4*)(attn + ((size_t)(idx4/192)*LSEQ + i)*LSEQ + (idx4%192)*4);
  }
  int c = t & 127, hb = (t >> 7) * 6;
  float acc[6] = {0.f,0.f,0.f,0.f,0.f,0.f};
  __syncthreads();
  for (int j0 = 0; j0 < LSEQ; j0 += 8){
    ((float4*)prT)[t] = *(const float4*)(pair + ((size_t)i*LSEQ + j0)*CZ + t*4);
    __syncthreads();
#pragma unroll
    for (int jj = 0; jj < 8; ++jj){
      float pv = prT[jj*CZ + c];
#pragma unroll
      for (int hh = 0; hh < 6; ++hh)
        acc[hh] += aT[(hb+hh)*LSEQ + j0 + jj] * pv;
    }
    __syncthreads();
  }
#pragma unroll
  for (int hh = 0; hh < 6; ++hh)
    cat[(size_t)i*OUTD + 672 + (hb+hh)*CZ + c] = acc[hh];
}

// ---------------- split-K reduce + bias ----------------
__global__ __launch_bounds__(256) void k_reduce(
    const float* __restrict__ part, const float* __restrict__ bias,
    float* __restrict__ out){
  int idx = blockIdx.x*256 + threadIdx.x;
  if (idx >= LSEQ*CS) return;
  float v = bias[idx % CS];
#pragma unroll
  for (int z = 0; z < 6; ++z) v += part[(size_t)z*LSEQ*CS + idx];
  out[idx] = v;
}

extern "C" void kernel_launch(void* const* d_in, const int* in_sizes, int n_in,
                              void* d_out, int out_size, void* d_ws, size_t ws_size,
                              hipStream_t stream){
  const float* single = (const float*)d_in[0];
  const float* pair   = (const float*)d_in[1];
  const float* rots   = (const float*)d_in[2];
  const float* trans  = (const float*)d_in[3];
  const float* ln_g   = (const float*)d_in[4];
  const float* ln_b   = (const float*)d_in[5];
  const float* Wq  = (const float*)d_in[6];
  const float* Wk  = (const float*)d_in[7];
  const float* Wv  = (const float*)d_in[8];
  const float* Wqp = (const float*)d_in[9];
  const float* bqp = (const float*)d_in[10];
  const float* Wkp = (const float*)d_in[11];
  const float* bkp = (const float*)d_in[12];
  const float* Wvp = (const float*)d_in[13];
  const float* bvp = (const float*)d_in[14];
  const float* Wpb = (const float*)d_in[15];
  const float* hw  = (const float*)d_in[16];
  const float* Wo  = (const float*)d_in[17];
  const float* bo  = (const float*)d_in[18];
  float* out = (float*)d_out;

  float* ws   = (float*)d_ws;
  float* s    = ws;                 // 294912
  float* q    = s + 294912;         // 294912
  float* kbuf = q + 294912;         // 294912
  float* vbuf = kbuf + 294912;      // 294912
  float* qp   = vbuf + 294912;      // 110592
  float* kp   = qp + 110592;        // 110592
  float* vp   = kp + 110592;        // 221184
  float* logits = vp + 221184;      // 7077888 (28.3 MB)
  float* bmat = logits + 7077888;   // 516096
  float* cat  = bmat + 516096;      // 1695744
  float* part = logits;             // reuse logits region for split-K partials

  k_layernorm<<<LSEQ, 128, 0, stream>>>(single, ln_g, ln_b, s);
  k_gemm<<<dim3(6,12,1),256,0,stream>>>(s, Wq,  nullptr, q,    768,384,384,384);
  k_gemm<<<dim3(6,12,1),256,0,stream>>>(s, Wk,  nullptr, kbuf, 768,384,384,384);
  k_gemm<<<dim3(6,12,1),256,0,stream>>>(s, Wv,  nullptr, vbuf, 768,384,384,384);
  k_gemm<<<dim3(3,12,1),256,0,stream>>>(s, Wqp, bqp,     qp,   768,144,384,384);
  k_gemm<<<dim3(3,12,1),256,0,stream>>>(s, Wkp, bkp,     kp,   768,144,384,384);
  k_gemm<<<dim3(5,12,1),256,0,stream>>>(s, Wvp, bvp,     vp,   768,288,384,384);
  k_frames<<<(LSEQ*48+255)/256,256,0,stream>>>(qp, rots, trans, 48);
  k_frames<<<(LSEQ*48+255)/256,256,0,stream>>>(kp, rots, trans, 48);
  k_frames<<<(LSEQ*96+255)/256,256,0,stream>>>(vp, rots, trans, 96);
  k_bmat<<<(NH*LSEQ*56+255)/256,256,0,stream>>>(vbuf, vp, bmat);
  k_qk<<<dim3(12,12,12),256,0,stream>>>(q, kbuf, logits);
  k_dist<<<dim3(768,24),256,0,stream>>>(qp, kp, hw, logits);
  k_pairbias<<<LL2/256,256,0,stream>>>(pair, Wpb, logits);
  k_softmax<<<NH*LSEQ,256,0,stream>>>(logits);
  k_pv<<<dim3(12,NH),256,0,stream>>>(logits, bmat, cat);
  k_outpts<<<(LSEQ*96+255)/256,256,0,stream>>>(rots, trans, cat);
  k_outpair<<<LSEQ,256,0,stream>>>(logits, pair, cat);
  k_gemm<<<dim3(6,12,6),256,0,stream>>>(cat, Wo, nullptr, part, 768,384,2208,368);
  k_reduce<<<(LSEQ*CS+255)/256,256,0,stream>>>(part, bo, out);
}

// Round 2
// 488.300 us; speedup vs baseline: 1.9373x; 1.9373x over previous
//
#include <hip/hip_runtime.h>
#include <math.h>

#define LSEQ 768
#define CS   384
#define CZ   128
#define NH   12
#define OUTD 2208
#define PROJW 1728   // [q 384 | k 384 | v 384 | qp 144 | kp 144 | vp 288]
#define TIL  64
#define NT   12

__device__ __forceinline__ float waveSum(float v){
#pragma unroll
  for (int o = 32; o > 0; o >>= 1) v += __shfl_down(v, o, 64);
  return v;
}

// ---------------- LayerNorm ----------------
__global__ __launch_bounds__(128) void k_layernorm(
    const float* __restrict__ x, const float* __restrict__ g,
    const float* __restrict__ b, float* __restrict__ s){
  int i = blockIdx.x, t = threadIdx.x;
  const float* row = x + (size_t)i*CS;
  float v0 = row[t], v1 = row[t+128], v2 = row[t+256];
  float sum = v0+v1+v2;
  float sq  = v0*v0+v1*v1+v2*v2;
  float ws1 = waveSum(sum), ws2 = waveSum(sq);
  __shared__ float red[4];
  int w = t>>6, lane = t&63;
  if (lane == 0){ red[w] = ws1; red[w+2] = ws2; }
  __syncthreads();
  float mu   = (red[0]+red[1]) * (1.f/CS);
  float var  = (red[2]+red[3]) * (1.f/CS) - mu*mu;
  float rstd = rsqrtf(var + 1e-5f);
  float* o = s + (size_t)i*CS;
  o[t]     = (v0-mu)*rstd*g[t]     + b[t];
  o[t+128] = (v1-mu)*rstd*g[t+128] + b[t+128];
  o[t+256] = (v2-mu)*rstd*g[t+256] + b[t+256];
}

// ---------------- concat weights into wcat[384][1728], bcat[1728] ----------------
__global__ void k_wcat(const float* __restrict__ Wq, const float* __restrict__ Wk,
                       const float* __restrict__ Wv, const float* __restrict__ Wqp,
                       const float* __restrict__ Wkp, const float* __restrict__ Wvp,
                       const float* __restrict__ bqp, const float* __restrict__ bkp,
                       const float* __restrict__ bvp,
                       float* __restrict__ wcat, float* __restrict__ bcat){
  int idx = blockIdx.x*256 + threadIdx.x;
  if (idx < PROJW){
    float bv = 0.f;
    if (idx >= 1440)      bv = bvp[idx-1440];
    else if (idx >= 1296) bv = bkp[idx-1296];
    else if (idx >= 1152) bv = bqp[idx-1152];
    bcat[idx] = bv;
  }
  if (idx >= 384*PROJW) return;
  int r = idx / PROJW, c = idx % PROJW;
  float v;
  if (c < 384)       v = Wq[r*384 + c];
  else if (c < 768)  v = Wk[r*384 + c-384];
  else if (c < 1152) v = Wv[r*384 + c-768];
  else if (c < 1296) v = Wqp[r*144 + c-1152];
  else if (c < 1440) v = Wkp[r*144 + c-1296];
  else               v = Wvp[r*288 + c-1440];
  wcat[idx] = v;
}

// ---------------- generic tiled GEMM (64x64, BK=16), optional split-K ----------------
__global__ __launch_bounds__(256) void k_gemm(
    const float* __restrict__ A, const float* __restrict__ B,
    const float* __restrict__ bias, float* __restrict__ C,
    int M, int N, int K, int kChunk){
  __shared__ float As[16][65];
  __shared__ float Bs[16][65];
  int j0 = blockIdx.x*64, i0 = blockIdx.y*64;
  int kBeg = blockIdx.z * kChunk;
  int t = threadIdx.x, tx = t & 15, ty = t >> 4;
  int arow = t >> 2, ak = (t & 3) * 4;
  int brow = t >> 4, bcol = (t & 15) * 4;
  float acc[4][4] = {};
  for (int kb = kBeg; kb < kBeg + kChunk; kb += 16){
    float4 av = *(const float4*)(A + (size_t)(i0+arow)*K + kb + ak);
    As[ak+0][arow]=av.x; As[ak+1][arow]=av.y; As[ak+2][arow]=av.z; As[ak+3][arow]=av.w;
    float4 bv = make_float4(0.f,0.f,0.f,0.f);
    if (j0 + bcol < N) bv = *(const float4*)(B + (size_t)(kb+brow)*N + j0 + bcol);
    Bs[brow][bcol+0]=bv.x; Bs[brow][bcol+1]=bv.y; Bs[brow][bcol+2]=bv.z; Bs[brow][bcol+3]=bv.w;
    __syncthreads();
#pragma unroll
    for (int kk = 0; kk < 16; ++kk){
      float a0=As[kk][ty*4+0],a1=As[kk][ty*4+1],a2=As[kk][ty*4+2],a3=As[kk][ty*4+3];
      float b0=Bs[kk][tx*4+0],b1=Bs[kk][tx*4+1],b2=Bs[kk][tx*4+2],b3=Bs[kk][tx*4+3];
      acc[0][0]+=a0*b0; acc[0][1]+=a0*b1; acc[0][2]+=a0*b2; acc[0][3]+=a0*b3;
      acc[1][0]+=a1*b0; acc[1][1]+=a1*b1; acc[1][2]+=a1*b2; acc[1][3]+=a1*b3;
      acc[2][0]+=a2*b0; acc[2][1]+=a2*b1; acc[2][2]+=a2*b2; acc[2][3]+=a2*b3;
      acc[3][0]+=a3*b0; acc[3][1]+=a3*b1; acc[3][2]+=a3*b2; acc[3][3]+=a3*b3;
    }
    __syncthreads();
  }
  size_t zoff = (size_t)blockIdx.z * M * N;
  bool noSplit = (gridDim.z == 1);
#pragma unroll
  for (int r = 0; r < 4; ++r){
    int i = i0 + ty*4 + r;
#pragma unroll
    for (int c = 0; c < 4; ++c){
      int j = j0 + tx*4 + c;
      if (j < N){
        float v = acc[r][c];
        if (noSplit && bias) v += bias[j];
        C[zoff + (size_t)i*N + j] = v;
      }
    }
  }
}

// ---------------- apply frames in-place on proj slices: p <- R p + t ----------------
__global__ void k_frames(float* __restrict__ proj, const float* __restrict__ rots,
                         const float* __restrict__ trans){
  int idx = blockIdx.x*256 + threadIdx.x;
  if (idx >= LSEQ*192) return;
  int i = idx/192, p = idx%192;
  int off = (p < 48) ? (1152 + p*3) : ((p < 96) ? (1296 + (p-48)*3) : (1440 + (p-96)*3));
  float* pp = proj + (size_t)i*PROJW + off;
  const float* R  = rots + i*9;
  const float* tr = trans + i*3;
  float x=pp[0], y=pp[1], z=pp[2];
  pp[0] = R[0]*x + R[1]*y + R[2]*z + tr[0];
  pp[1] = R[3]*x + R[4]*y + R[5]*z + tr[1];
  pp[2] = R[6]*x + R[7]*y + R[8]*z + tr[2];
}

// ---------------- fused flash-IPA: block per query i ----------------
// waves 0-3: pairbias; waves 4-7: qk+dist; online softmax; PV + outpair fused.
__global__ __launch_bounds__(512) void k_fused(
    const float* __restrict__ proj, const float* __restrict__ pair,
    const float* __restrict__ Wpb, const float* __restrict__ hw,
    const float* __restrict__ rots, const float* __restrict__ trans,
    float* __restrict__ cat){
  const int i = blockIdx.x;
  const int t = threadIdx.x;
  __shared__ float qs[CS];        // q row (scalar q)
  __shared__ float qgs[144];      // q_g row (frame-transformed pts)
  __shared__ float wpb[1536];     // Wpb [c][h]
  __shared__ float wcs[12];       // softplus(head_weights)
  __shared__ float S[12*66];      // scores -> probs tile (padded 66)
  __shared__ float Spb[12*66];    // pairbias tile
  __shared__ float m_run[12], l_run[12], scb[12];
  __shared__ float outbuf[288];
  __shared__ float Ri[9], ti[3];

  const float* prow_i = proj + (size_t)i*PROJW;
  if (t < CS)  qs[t]  = prow_i[t];
  if (t < 144) qgs[t] = prow_i[1152 + t];
  wpb[t] = Wpb[t]; wpb[t+512] = Wpb[t+512]; wpb[t+1024] = Wpb[t+1024];
  if (t < 12){ wcs[t] = log1pf(__expf(hw[t])); m_run[t] = -1e30f; l_run[t] = 0.f; }
  if (t < 9) Ri[t] = rots[i*9+t];
  if (t < 3) ti[t] = trans[i*3+t];

  // C1 state: thread t<168 owns 4 consecutive outputs n0..n0+3 of [v(384)|vg(288)]
  float accS0=0.f, accS1=0.f, accS2=0.f, accS3=0.f;
  const int n0 = 4*t;
  const int hC1 = (t < 96) ? (n0 >> 5) : ((t - 96) / 6);
  const size_t offC1 = (t < 96) ? (size_t)(768 + n0) : (size_t)(1440 + (n0 - 384));
  // C2 state: c2 = pair channel, 3 heads per thread
  float accP0=0.f, accP1=0.f, accP2=0.f;
  const int c2 = t & 127, g2 = t >> 7;

  __syncthreads();

  for (int jt = 0; jt < NT; ++jt){
    const int j0 = jt*TIL;
    // ================= A: scores =================
    if (t < 256){
      // pairbias rows j0..j0+63: quad (4 lanes) per row, 64B fully-consumed lines
      const int jl = t >> 2, q = t & 3;
      const float* prow = pair + ((size_t)i*LSEQ + j0 + jl)*CZ + q*4;
      float acc[12];
#pragma unroll
      for (int h=0;h<12;++h) acc[h]=0.f;
#pragma unroll
      for (int c4 = 0; c4 < 8; ++c4){
        float4 pv = *(const float4*)(prow + c4*16);
        const float* wb = &wpb[(c4*16 + q*4)*12];
#pragma unroll
        for (int cc = 0; cc < 4; ++cc){
          float p = (&pv.x)[cc];
          float4 wA = *(const float4*)(wb + cc*12);
          float4 wB = *(const float4*)(wb + cc*12 + 4);
          float4 wC = *(const float4*)(wb + cc*12 + 8);
          acc[0]+=p*wA.x; acc[1]+=p*wA.y; acc[2] +=p*wA.z; acc[3] +=p*wA.w;
          acc[4]+=p*wB.x; acc[5]+=p*wB.y; acc[6] +=p*wB.z; acc[7] +=p*wB.w;
          acc[8]+=p*wC.x; acc[9]+=p*wC.y; acc[10]+=p*wC.z; acc[11]+=p*wC.w;
        }
      }
#pragma unroll
      for (int h=0;h<12;++h){
        acc[h] += __shfl_xor(acc[h], 1);
        acc[h] += __shfl_xor(acc[h], 2);
      }
      float v0=acc[0], v1=acc[4], v2=acc[8];
      if (q==1){ v0=acc[1]; v1=acc[5]; v2=acc[9]; }
      if (q==2){ v0=acc[2]; v1=acc[6]; v2=acc[10]; }
      if (q==3){ v0=acc[3]; v1=acc[7]; v2=acc[11]; }
      Spb[q*66+jl] = v0; Spb[(q+4)*66+jl] = v1; Spb[(q+8)*66+jl] = v2;
    } else {
      // qk + dist: thread per (j, 3-head group)
      const int u = t-256, jl = u & 63, g = u >> 6;
      const float* krow  = proj + (size_t)(j0+jl)*PROJW + 384 + g*96;
      const float* kgrow = proj + (size_t)(j0+jl)*PROJW + 1296 + g*36;
#pragma unroll
      for (int e = 0; e < 3; ++e){
        const int h = 3*g + e;
        float s = 0.f;
#pragma unroll
        for (int d4 = 0; d4 < 8; ++d4){
          float4 kv = *(const float4*)(krow + e*32 + d4*4);
          s += kv.x*qs[h*32+d4*4] + kv.y*qs[h*32+d4*4+1]
             + kv.z*qs[h*32+d4*4+2] + kv.w*qs[h*32+d4*4+3];
        }
        float d2 = 0.f;
#pragma unroll
        for (int pq = 0; pq < 3; ++pq){
          float4 kgv = *(const float4*)(kgrow + e*12 + pq*4);
          float dx = qgs[h*12+pq*4+0]-kgv.x;
          float dy = qgs[h*12+pq*4+1]-kgv.y;
          float dz = qgs[h*12+pq*4+2]-kgv.z;
          float dw = qgs[h*12+pq*4+3]-kgv.w;
          d2 += dx*dx + dy*dy + dz*dz + dw*dw;
        }
        S[h*66+jl] = s*0.17677669529663687f - 0.5f*wcs[h]*d2;
      }
    }
    __syncthreads();
    // ================= online softmax update =================
    {
      const int w = t >> 6;
      if (w < 6){
        const int lane = t & 63, half = lane >> 5, jj = lane & 31;
        const int h = 2*w + half;
        float s0 = S[h*66+jj]    + Spb[h*66+jj];
        float s1 = S[h*66+jj+32] + Spb[h*66+jj+32];
        float mt = fmaxf(s0, s1);
#pragma unroll
        for (int m=16;m>0;m>>=1) mt = fmaxf(mt, __shfl_xor(mt, m));
        float mo = m_run[h];
        float mn = fmaxf(mo, mt);
        float p0 = __expf(s0-mn), p1 = __expf(s1-mn);
        float ts = p0 + p1;
#pragma unroll
        for (int m=16;m>0;m>>=1) ts += __shfl_xor(ts, m);
        S[h*66+jj] = p0; S[h*66+jj+32] = p1;
        if (jj == 0){
          float scv = __expf(mo - mn);
          scb[h] = scv;
          l_run[h] = l_run[h]*scv + ts;
          m_run[h] = mn;
        }
      }
    }
    __syncthreads();
    // ================= C: accumulate PV + outpair =================
    {
      // C2: out_pair (all 512 threads)
      float s0 = scb[3*g2], s1 = scb[3*g2+1], s2 = scb[3*g2+2];
      accP0 *= s0; accP1 *= s1; accP2 *= s2;
      const float* p2 = pair + ((size_t)i*LSEQ + j0)*CZ + c2;
#pragma unroll 4
      for (int jj = 0; jj < TIL; ++jj){
        float pv = p2[(size_t)jj*CZ];
        accP0 += S[(3*g2+0)*66+jj]*pv;
        accP1 += S[(3*g2+1)*66+jj]*pv;
        accP2 += S[(3*g2+2)*66+jj]*pv;
      }
      // C1: out_scalar + out_pts (threads 0..167)
      if (t < 168){
        float scv = scb[hC1];
        accS0 *= scv; accS1 *= scv; accS2 *= scv; accS3 *= scv;
        const float* b = proj + offC1;
#pragma unroll 4
        for (int jj = 0; jj < TIL; ++jj){
          float4 bv = *(const float4*)(b + (size_t)(j0+jj)*PROJW);
          float p = S[hC1*66+jj];
          accS0 += p*bv.x; accS1 += p*bv.y; accS2 += p*bv.z; accS3 += p*bv.w;
        }
      }
    }
    __syncthreads();
  }
  // ================= epilogue =================
  float* crow = cat + (size_t)i*OUTD;
  if (t < 168){
    float linv = 1.f/l_run[hC1];
    float o0=accS0*linv, o1=accS1*linv, o2=accS2*linv, o3=accS3*linv;
    if (t < 96){
      crow[n0]=o0; crow[n0+1]=o1; crow[n0+2]=o2; crow[n0+3]=o3;
    } else {
      outbuf[n0-384]=o0; outbuf[n0-383]=o1; outbuf[n0-382]=o2; outbuf[n0-381]=o3;
    }
  }
  {
    float l0=1.f/l_run[3*g2], l1=1.f/l_run[3*g2+1], l2=1.f/l_run[3*g2+2];
    crow[672 + (3*g2+0)*128 + c2] = accP0*l0;
    crow[672 + (3*g2+1)*128 + c2] = accP1*l1;
    crow[672 + (3*g2+2)*128 + c2] = accP2*l2;
  }
  __syncthreads();
  if (t < 96){
    float x = outbuf[3*t]-ti[0], y = outbuf[3*t+1]-ti[1], z = outbuf[3*t+2]-ti[2];
    crow[384+3*t+0] = Ri[0]*x + Ri[3]*y + Ri[6]*z;
    crow[384+3*t+1] = Ri[1]*x + Ri[4]*y + Ri[7]*z;
    crow[384+3*t+2] = Ri[2]*x + Ri[5]*y + Ri[8]*z;
  }
}

// ---------------- split-K reduce + bias ----------------
__global__ __launch_bounds__(256) void k_reduce(
    const float* __restrict__ part, const float* __restrict__ bias,
    float* __restrict__ out){
  int idx = blockIdx.x*256 + threadIdx.x;
  if (idx >= LSEQ*CS) return;
  float v = bias[idx % CS];
#pragma unroll
  for (int z = 0; z < 6; ++z) v += part[(size_t)z*LSEQ*CS + idx];
  out[idx] = v;
}

extern "C" void kernel_launch(void* const* d_in, const int* in_sizes, int n_in,
                              void* d_out, int out_size, void* d_ws, size_t ws_size,
                              hipStream_t stream){
  const float* single = (const float*)d_in[0];
  const float* pair   = (const float*)d_in[1];
  const float* rots   = (const float*)d_in[2];
  const float* trans  = (const float*)d_in[3];
  const float* ln_g   = (const float*)d_in[4];
  const float* ln_b   = (const float*)d_in[5];
  const float* Wq  = (const float*)d_in[6];
  const float* Wk  = (const float*)d_in[7];
  const float* Wv  = (const float*)d_in[8];
  const float* Wqp = (const float*)d_in[9];
  const float* bqp = (const float*)d_in[10];
  const float* Wkp = (const float*)d_in[11];
  const float* bkp = (const float*)d_in[12];
  const float* Wvp = (const float*)d_in[13];
  const float* bvp = (const float*)d_in[14];
  const float* Wpb = (const float*)d_in[15];
  const float* hw  = (const float*)d_in[16];
  const float* Wo  = (const float*)d_in[17];
  const float* bo  = (const float*)d_in[18];
  float* out = (float*)d_out;

  float* ws   = (float*)d_ws;
  float* s    = ws;                   // 294912
  float* wcat = s + 294912;           // 663552
  float* bcat = wcat + 663552;        // 1728 (+pad)
  float* proj = bcat + 1792;          // 1327104
  float* cat  = proj + 1327104;       // 1695744
  float* part = cat + 1695744;        // 1769472

  k_layernorm<<<LSEQ, 128, 0, stream>>>(single, ln_g, ln_b, s);
  k_wcat<<<(384*PROJW+255)/256, 256, 0, stream>>>(Wq,Wk,Wv,Wqp,Wkp,Wvp,bqp,bkp,bvp,wcat,bcat);
  k_gemm<<<dim3(27,12,1), 256, 0, stream>>>(s, wcat, bcat, proj, 768, PROJW, 384, 384);
  k_frames<<<(LSEQ*192+255)/256, 256, 0, stream>>>(proj, rots, trans);
  k_fused<<<LSEQ, 512, 0, stream>>>(proj, pair, Wpb, hw, rots, trans, cat);
  k_gemm<<<dim3(6,12,6), 256, 0, stream>>>(cat, Wo, nullptr, part, 768, 384, OUTD, 368);
  k_reduce<<<(LSEQ*CS+255)/256, 256, 0, stream>>>(part, bo, out);
}

// Round 3
// 473.457 us; speedup vs baseline: 1.9981x; 1.0314x over previous
//
#include <hip/hip_runtime.h>
#include <math.h>

#define LSEQ 768
#define CS   384
#define CZ   128
#define NH   12
#define OUTD 2208
#define PROJW 1728   // [q 384 | k 384 | v 384 | qp 144 | kp 144 | vp 288]
#define TIL  64
#define NT   12

__device__ __forceinline__ float waveSum(float v){
#pragma unroll
  for (int o = 32; o > 0; o >>= 1) v += __shfl_down(v, o, 64);
  return v;
}

// ---------------- LayerNorm ----------------
__global__ __launch_bounds__(128) void k_layernorm(
    const float* __restrict__ x, const float* __restrict__ g,
    const float* __restrict__ b, float* __restrict__ s){
  int i = blockIdx.x, t = threadIdx.x;
  const float* row = x + (size_t)i*CS;
  float v0 = row[t], v1 = row[t+128], v2 = row[t+256];
  float sum = v0+v1+v2;
  float sq  = v0*v0+v1*v1+v2*v2;
  float ws1 = waveSum(sum), ws2 = waveSum(sq);
  __shared__ float red[4];
  int w = t>>6, lane = t&63;
  if (lane == 0){ red[w] = ws1; red[w+2] = ws2; }
  __syncthreads();
  float mu   = (red[0]+red[1]) * (1.f/CS);
  float var  = (red[2]+red[3]) * (1.f/CS) - mu*mu;
  float rstd = rsqrtf(var + 1e-5f);
  float* o = s + (size_t)i*CS;
  o[t]     = (v0-mu)*rstd*g[t]     + b[t];
  o[t+128] = (v1-mu)*rstd*g[t+128] + b[t+128];
  o[t+256] = (v2-mu)*rstd*g[t+256] + b[t+256];
}

// ---------------- concat weights into wcat[384][1728], bcat[1728] ----------------
__global__ void k_wcat(const float* __restrict__ Wq, const float* __restrict__ Wk,
                       const float* __restrict__ Wv, const float* __restrict__ Wqp,
                       const float* __restrict__ Wkp, const float* __restrict__ Wvp,
                       const float* __restrict__ bqp, const float* __restrict__ bkp,
                       const float* __restrict__ bvp,
                       float* __restrict__ wcat, float* __restrict__ bcat){
  int idx = blockIdx.x*256 + threadIdx.x;
  if (idx < PROJW){
    float bv = 0.f;
    if (idx >= 1440)      bv = bvp[idx-1440];
    else if (idx >= 1296) bv = bkp[idx-1296];
    else if (idx >= 1152) bv = bqp[idx-1152];
    bcat[idx] = bv;
  }
  if (idx >= 384*PROJW) return;
  int r = idx / PROJW, c = idx % PROJW;
  float v;
  if (c < 384)       v = Wq[r*384 + c];
  else if (c < 768)  v = Wk[r*384 + c-384];
  else if (c < 1152) v = Wv[r*384 + c-768];
  else if (c < 1296) v = Wqp[r*144 + c-1152];
  else if (c < 1440) v = Wkp[r*144 + c-1296];
  else               v = Wvp[r*288 + c-1440];
  wcat[idx] = v;
}

// ---------------- generic tiled GEMM (64x64, BK=16), optional split-K ----------------
__global__ __launch_bounds__(256) void k_gemm(
    const float* __restrict__ A, const float* __restrict__ B,
    const float* __restrict__ bias, float* __restrict__ C,
    int M, int N, int K, int kChunk){
  __shared__ float As[16][65];
  __shared__ float Bs[16][65];
  int j0 = blockIdx.x*64, i0 = blockIdx.y*64;
  int kBeg = blockIdx.z * kChunk;
  int t = threadIdx.x, tx = t & 15, ty = t >> 4;
  int arow = t >> 2, ak = (t & 3) * 4;
  int brow = t >> 4, bcol = (t & 15) * 4;
  float acc[4][4] = {};
  for (int kb = kBeg; kb < kBeg + kChunk; kb += 16){
    float4 av = *(const float4*)(A + (size_t)(i0+arow)*K + kb + ak);
    As[ak+0][arow]=av.x; As[ak+1][arow]=av.y; As[ak+2][arow]=av.z; As[ak+3][arow]=av.w;
    float4 bv = make_float4(0.f,0.f,0.f,0.f);
    if (j0 + bcol < N) bv = *(const float4*)(B + (size_t)(kb+brow)*N + j0 + bcol);
    Bs[brow][bcol+0]=bv.x; Bs[brow][bcol+1]=bv.y; Bs[brow][bcol+2]=bv.z; Bs[brow][bcol+3]=bv.w;
    __syncthreads();
#pragma unroll
    for (int kk = 0; kk < 16; ++kk){
      float a0=As[kk][ty*4+0],a1=As[kk][ty*4+1],a2=As[kk][ty*4+2],a3=As[kk][ty*4+3];
      float b0=Bs[kk][tx*4+0],b1=Bs[kk][tx*4+1],b2=Bs[kk][tx*4+2],b3=Bs[kk][tx*4+3];
      acc[0][0]+=a0*b0; acc[0][1]+=a0*b1; acc[0][2]+=a0*b2; acc[0][3]+=a0*b3;
      acc[1][0]+=a1*b0; acc[1][1]+=a1*b1; acc[1][2]+=a1*b2; acc[1][3]+=a1*b3;
      acc[2][0]+=a2*b0; acc[2][1]+=a2*b1; acc[2][2]+=a2*b2; acc[2][3]+=a2*b3;
      acc[3][0]+=a3*b0; acc[3][1]+=a3*b1; acc[3][2]+=a3*b2; acc[3][3]+=a3*b3;
    }
    __syncthreads();
  }
  size_t zoff = (size_t)blockIdx.z * M * N;
  bool noSplit = (gridDim.z == 1);
#pragma unroll
  for (int r = 0; r < 4; ++r){
    int i = i0 + ty*4 + r;
#pragma unroll
    for (int c = 0; c < 4; ++c){
      int j = j0 + tx*4 + c;
      if (j < N){
        float v = acc[r][c];
        if (noSplit && bias) v += bias[j];
        C[zoff + (size_t)i*N + j] = v;
      }
    }
  }
}

// ---------------- apply frames in-place on proj slices: p <- R p + t ----------------
__global__ void k_frames(float* __restrict__ proj, const float* __restrict__ rots,
                         const float* __restrict__ trans){
  int idx = blockIdx.x*256 + threadIdx.x;
  if (idx >= LSEQ*192) return;
  int i = idx/192, p = idx%192;
  int off = (p < 48) ? (1152 + p*3) : ((p < 96) ? (1296 + (p-48)*3) : (1440 + (p-96)*3));
  float* pp = proj + (size_t)i*PROJW + off;
  const float* R  = rots + i*9;
  const float* tr = trans + i*3;
  float x=pp[0], y=pp[1], z=pp[2];
  pp[0] = R[0]*x + R[1]*y + R[2]*z + tr[0];
  pp[1] = R[3]*x + R[4]*y + R[5]*z + tr[1];
  pp[2] = R[6]*x + R[7]*y + R[8]*z + tr[2];
}

// ---------------- build Qa/Ka (K=44, padded 48) + norm biases ----------------
// Qa = [q/sqrt(32), wc*qg], Ka = [k, kg]; nrm[h][i] = -0.5*wc*|qg|^2 (and kg for nk)
__global__ __launch_bounds__(256) void k_prep(
    const float* __restrict__ proj, const float* __restrict__ hw,
    float* __restrict__ Qa, float* __restrict__ Ka, float* __restrict__ nrm){
  int i = blockIdx.x, t = threadIdx.x;
  __shared__ float wcl[12];
  if (t < 12) wcl[t] = log1pf(__expf(hw[t]));
  __syncthreads();
  const float* prow = proj + (size_t)i*PROJW;
  const float isq = 0.17677669529663687f;
  for (int idx = t; idx < 576; idx += 256){
    int h = idx/48, d = idx%48;
    float qv = 0.f, kv = 0.f;
    if (d < 32){ qv = prow[h*32 + d]*isq; kv = prow[384 + h*32 + d]; }
    else if (d < 44){ qv = prow[1152 + h*12 + (d-32)]*wcl[h]; kv = prow[1296 + h*12 + (d-32)]; }
    Qa[((size_t)h*LSEQ + i)*48 + d] = qv;
    Ka[((size_t)h*LSEQ + i)*48 + d] = kv;
  }
  if (t < 24){
    int h = t % 12; int isK = (t >= 12) ? 1 : 0;
    const float* g = prow + (isK ? 1296 : 1152) + h*12;
    float sum = 0.f;
#pragma unroll
    for (int d = 0; d < 12; ++d) sum += g[d]*g[d];
    nrm[((size_t)(isK*12 + h))*LSEQ + i] = -0.5f*wcl[h]*sum;
  }
}

// ---------------- logits GEMM: logits[h][i][j] = Qa_i . Ka_j + nq[i] + nk[j] ----------------
__global__ __launch_bounds__(256) void k_qkaug(
    const float* __restrict__ Qa, const float* __restrict__ Ka,
    const float* __restrict__ nrm, float* __restrict__ logits){
  int j0 = blockIdx.x*64, i0 = blockIdx.y*64, h = blockIdx.z;
  __shared__ float Qs[64*49], Ks[64*49];
  __shared__ float nq[64], nk[64];
  int t = threadIdx.x;
  for (int idx = t; idx < 768; idx += 256){
    int row = idx/12, c4 = (idx%12)*4;
    float4 qv = *(const float4*)(Qa + ((size_t)h*LSEQ + i0+row)*48 + c4);
    Qs[row*49+c4]=qv.x; Qs[row*49+c4+1]=qv.y; Qs[row*49+c4+2]=qv.z; Qs[row*49+c4+3]=qv.w;
    float4 kv = *(const float4*)(Ka + ((size_t)h*LSEQ + j0+row)*48 + c4);
    Ks[row*49+c4]=kv.x; Ks[row*49+c4+1]=kv.y; Ks[row*49+c4+2]=kv.z; Ks[row*49+c4+3]=kv.w;
  }
  if (t < 64) nq[t] = nrm[(size_t)h*LSEQ + i0 + t];
  else if (t < 128) nk[t-64] = nrm[(size_t)(12+h)*LSEQ + j0 + (t-64)];
  __syncthreads();
  int tx = t & 15, ty = t >> 4;
  float acc[4][4] = {};
#pragma unroll 4
  for (int k = 0; k < 44; ++k){
    float a0=Qs[(ty*4+0)*49+k], a1=Qs[(ty*4+1)*49+k], a2=Qs[(ty*4+2)*49+k], a3=Qs[(ty*4+3)*49+k];
    float b0=Ks[(tx*4+0)*49+k], b1=Ks[(tx*4+1)*49+k], b2=Ks[(tx*4+2)*49+k], b3=Ks[(tx*4+3)*49+k];
    acc[0][0]+=a0*b0; acc[0][1]+=a0*b1; acc[0][2]+=a0*b2; acc[0][3]+=a0*b3;
    acc[1][0]+=a1*b0; acc[1][1]+=a1*b1; acc[1][2]+=a1*b2; acc[1][3]+=a1*b3;
    acc[2][0]+=a2*b0; acc[2][1]+=a2*b1; acc[2][2]+=a2*b2; acc[2][3]+=a2*b3;
    acc[3][0]+=a3*b0; acc[3][1]+=a3*b1; acc[3][2]+=a3*b2; acc[3][3]+=a3*b3;
  }
  float nq0=nq[ty*4], nq1=nq[ty*4+1], nq2=nq[ty*4+2], nq3=nq[ty*4+3];
  float nk0=nk[tx*4], nk1=nk[tx*4+1], nk2=nk[tx*4+2], nk3=nk[tx*4+3];
  float nqa[4] = {nq0,nq1,nq2,nq3};
#pragma unroll
  for (int r = 0; r < 4; ++r){
    float4 o = make_float4(acc[r][0]+nqa[r]+nk0, acc[r][1]+nqa[r]+nk1,
                           acc[r][2]+nqa[r]+nk2, acc[r][3]+nqa[r]+nk3);
    *(float4*)(logits + ((size_t)h*LSEQ + i0+ty*4+r)*LSEQ + j0 + tx*4) = o;
  }
}

// ---------------- fused: pairbias + online softmax + out_pair; block per i ----------------
__global__ __launch_bounds__(512, 6) void k_fused2(
    const float* __restrict__ pair, const float* __restrict__ Wpb,
    float* __restrict__ attn,   // logits in -> unnormalized probs out (in-place)
    float* __restrict__ fac,    // [768][12][12] per-tile correction incl 1/l
    float* __restrict__ cat){
  const int i = blockIdx.x, t = threadIdx.x;
  __shared__ __align__(16) float pairT[64*132];
  __shared__ __align__(16) float wpbT[12*160];  // [h][cseg*20 + m]
  __shared__ __align__(16) float S[12*68];
  __shared__ float m_run[12], l_run[12], scb[12];
  __shared__ float mh[12][12];  // [tile][h]

  for (int idx = t; idx < 1536; idx += 512){
    int c = idx/12, h = idx%12;
    wpbT[h*160 + (c>>4)*20 + (c&15)] = Wpb[idx];
  }
  if (t < 12){ m_run[t] = -1e30f; l_run[t] = 0.f; }

  const int jl = t>>3, cseg = t&7;
  const float* psrc = pair + ((size_t)i*LSEQ + jl)*CZ + cseg*16;
  float4 pf0 = *(const float4*)(psrc);
  float4 pf1 = *(const float4*)(psrc+4);
  float4 pf2 = *(const float4*)(psrc+8);
  float4 pf3 = *(const float4*)(psrc+12);

  const int sh = 2*(t>>6) + ((t>>5)&1);  // softmax head (t<384)
  const int sjj = t&31;
  float* lrow = attn + ((size_t)sh*LSEQ + i)*LSEQ + sjj;
  float gl0 = 0.f, gl1 = 0.f;
  if (t < 384){ gl0 = lrow[0]; gl1 = lrow[32]; }

  const int c2 = t&127, g2 = t>>7;
  float accP0 = 0.f, accP1 = 0.f, accP2 = 0.f;

  __syncthreads();

  for (int jt = 0; jt < NT; ++jt){
    const int j0 = jt*TIL;
    // ---- pairbias from prefetch registers ----
    float acc[12];
    const float* wb = wpbT + cseg*20;
#pragma unroll
    for (int h = 0; h < 12; ++h){
      float4 w0 = *(const float4*)(wb + h*160);
      float4 w1 = *(const float4*)(wb + h*160 + 4);
      float4 w2 = *(const float4*)(wb + h*160 + 8);
      float4 w3 = *(const float4*)(wb + h*160 + 12);
      acc[h] = pf0.x*w0.x + pf0.y*w0.y + pf0.z*w0.z + pf0.w*w0.w
             + pf1.x*w1.x + pf1.y*w1.y + pf1.z*w1.z + pf1.w*w1.w
             + pf2.x*w2.x + pf2.y*w2.y + pf2.z*w2.z + pf2.w*w2.w
             + pf3.x*w3.x + pf3.y*w3.y + pf3.z*w3.z + pf3.w*w3.w;
    }
#pragma unroll
    for (int h = 0; h < 12; ++h){
      acc[h] += __shfl_xor(acc[h], 1);
      acc[h] += __shfl_xor(acc[h], 2);
      acc[h] += __shfl_xor(acc[h], 4);
    }
    S[cseg*68 + jl] = acc[cseg];
    if (cseg < 4) S[(8+cseg)*68 + jl] = acc[8+cseg];
    // ---- stash tile in LDS for out_pair ----
    float* pd = pairT + jl*132 + cseg*16;
    *(float4*)(pd)   = pf0; *(float4*)(pd+4)  = pf1;
    *(float4*)(pd+8) = pf2; *(float4*)(pd+12) = pf3;
    __syncthreads();
    // ---- prefetch next tile + next logits (in flight under softmax+C2) ----
    if (jt < 11){
      const float* pn = pair + ((size_t)i*LSEQ + j0+64 + jl)*CZ + cseg*16;
      pf0 = *(const float4*)(pn);   pf1 = *(const float4*)(pn+4);
      pf2 = *(const float4*)(pn+8); pf3 = *(const float4*)(pn+12);
    }
    float ngl0 = 0.f, ngl1 = 0.f;
    if (t < 384 && jt < 11){ ngl0 = lrow[j0+64]; ngl1 = lrow[j0+96]; }
    // ---- online softmax (waves 0..5, half-wave per head) ----
    if (t < 384){
      float s0 = S[sh*68 + sjj]      + gl0;
      float s1 = S[sh*68 + sjj + 32] + gl1;
      float mt = fmaxf(s0, s1);
#pragma unroll
      for (int m = 16; m > 0; m >>= 1) mt = fmaxf(mt, __shfl_xor(mt, m));
      float mo = m_run[sh], mn = fmaxf(mo, mt);
      float p0 = __expf(s0 - mn), p1 = __expf(s1 - mn);
      float ts = p0 + p1;
#pragma unroll
      for (int m = 16; m > 0; m >>= 1) ts += __shfl_xor(ts, m);
      S[sh*68 + sjj] = p0; S[sh*68 + sjj + 32] = p1;
      lrow[j0] = p0; lrow[j0 + 32] = p1;
      if (sjj == 0){
        float sc = __expf(mo - mn);
        scb[sh] = sc; l_run[sh] = l_run[sh]*sc + ts; m_run[sh] = mn;
        mh[jt][sh] = mn;
      }
      gl0 = ngl0; gl1 = ngl1;
    }
    __syncthreads();
    // ---- out_pair accumulate from LDS ----
    {
      float sc0 = scb[3*g2], sc1 = scb[3*g2+1], sc2 = scb[3*g2+2];
      accP0 *= sc0; accP1 *= sc1; accP2 *= sc2;
      const float* pcol = pairT + c2;
      const float* S0 = S + (3*g2)*68;
      const float* S1 = S0 + 68;
      const float* S2 = S1 + 68;
#pragma unroll
      for (int q = 0; q < 16; ++q){
        float pv0 = pcol[(4*q+0)*132], pv1 = pcol[(4*q+1)*132],
              pv2 = pcol[(4*q+2)*132], pv3 = pcol[(4*q+3)*132];
        float4 a = *(const float4*)(S0 + 4*q);
        float4 b = *(const float4*)(S1 + 4*q);
        float4 c = *(const float4*)(S2 + 4*q);
        accP0 += pv0*a.x + pv1*a.y + pv2*a.z + pv3*a.w;
        accP1 += pv0*b.x + pv1*b.y + pv2*b.z + pv3*b.w;
        accP2 += pv0*c.x + pv1*c.y + pv2*c.z + pv3*c.w;
      }
    }
    __syncthreads();
  }
  // ---- epilogue ----
  float* crow = cat + (size_t)i*OUTD + 672;
  crow[(3*g2+0)*CZ + c2] = accP0 / l_run[3*g2+0];
  crow[(3*g2+1)*CZ + c2] = accP1 / l_run[3*g2+1];
  crow[(3*g2+2)*CZ + c2] = accP2 / l_run[3*g2+2];
  if (t < 144){
    int h = t/12, tile = t%12;
    fac[(size_t)i*144 + t] = __expf(mh[tile][h] - m_run[h]) / l_run[h];
  }
}

// ---------------- PV GEMM: cat[v|pts_g] = (attn*fac) @ [v|vg] ----------------
__global__ __launch_bounds__(256) void k_pv(
    const float* __restrict__ attn, const float* __restrict__ proj,
    const float* __restrict__ fac, float* __restrict__ cat){
  int h = blockIdx.y, i0 = blockIdx.x*64;
  __shared__ float As[32][65];
  __shared__ float Bs[32][57];
  __shared__ float facs[64][12];
  int t = threadIdx.x, tx = t & 15, ty = t >> 4;
  for (int idx = t; idx < 768; idx += 256){
    int row = idx/12, tile = idx%12;
    facs[row][tile] = fac[(size_t)(i0+row)*144 + h*12 + tile];
  }
  float acc[4][4] = {};
  for (int kb = 0; kb < LSEQ; kb += 32){
    __syncthreads();
    for (int idx = t; idx < 512; idx += 256){
      int row = idx >> 3, k4 = (idx & 7)*4;
      float4 av = *(const float4*)(attn + ((size_t)h*LSEQ + i0 + row)*LSEQ + kb + k4);
      float fm = facs[row][kb>>6];
      As[k4+0][row]=av.x*fm; As[k4+1][row]=av.y*fm; As[k4+2][row]=av.z*fm; As[k4+3][row]=av.w*fm;
    }
    for (int idx = t; idx < 32*56; idx += 256){
      int kk = idx/56, n = idx%56;
      const float* prow = proj + (size_t)(kb+kk)*PROJW;
      Bs[kk][n] = (n < 32) ? prow[768 + h*32 + n] : prow[1440 + h*24 + (n-32)];
    }
    __syncthreads();
#pragma unroll
    for (int kk = 0; kk < 32; ++kk){
      float a0=As[kk][ty*4+0],a1=As[kk][ty*4+1],a2=As[kk][ty*4+2],a3=As[kk][ty*4+3];
      float b0=Bs[kk][tx*4+0],b1=Bs[kk][tx*4+1],b2=Bs[kk][tx*4+2],b3=Bs[kk][tx*4+3];
      acc[0][0]+=a0*b0; acc[0][1]+=a0*b1; acc[0][2]+=a0*b2; acc[0][3]+=a0*b3;
      acc[1][0]+=a1*b0; acc[1][1]+=a1*b1; acc[1][2]+=a1*b2; acc[1][3]+=a1*b3;
      acc[2][0]+=a2*b0; acc[2][1]+=a2*b1; acc[2][2]+=a2*b2; acc[2][3]+=a2*b3;
      acc[3][0]+=a3*b0; acc[3][1]+=a3*b1; acc[3][2]+=a3*b2; acc[3][3]+=a3*b3;
    }
  }
#pragma unroll
  for (int r = 0; r < 4; ++r){
    int i = i0 + ty*4 + r;
#pragma unroll
    for (int c = 0; c < 4; ++c){
      int n = tx*4 + c;
      float val = acc[r][c];
      if (n < 32)      cat[(size_t)i*OUTD + h*32 + n] = val;
      else if (n < 56) cat[(size_t)i*OUTD + 384 + h*24 + (n-32)] = val;
    }
  }
}

// ---------------- rotate output points back to local frame ----------------
__global__ void k_outpts(const float* __restrict__ rots, const float* __restrict__ trans,
                         float* __restrict__ cat){
  int idx = blockIdx.x*256 + threadIdx.x;
  if (idx >= LSEQ*96) return;
  int i = idx/96, n = idx%96;
  float* p = cat + (size_t)i*OUTD + 384 + n*3;
  const float* R  = rots + i*9;
  const float* tr = trans + i*3;
  float x = p[0]-tr[0], y = p[1]-tr[1], z = p[2]-tr[2];
  p[0] = R[0]*x + R[3]*y + R[6]*z;
  p[1] = R[1]*x + R[4]*y + R[7]*z;
  p[2] = R[2]*x + R[5]*y + R[8]*z;
}

// ---------------- split-K reduce + bias ----------------
__global__ __launch_bounds__(256) void k_reduce(
    const float* __restrict__ part, const float* __restrict__ bias,
    float* __restrict__ out){
  int idx = blockIdx.x*256 + threadIdx.x;
  if (idx >= LSEQ*CS) return;
  float v = bias[idx % CS];
#pragma unroll
  for (int z = 0; z < 6; ++z) v += part[(size_t)z*LSEQ*CS + idx];
  out[idx] = v;
}

extern "C" void kernel_launch(void* const* d_in, const int* in_sizes, int n_in,
                              void* d_out, int out_size, void* d_ws, size_t ws_size,
                              hipStream_t stream){
  const float* single = (const float*)d_in[0];
  const float* pair   = (const float*)d_in[1];
  const float* rots   = (const float*)d_in[2];
  const float* trans  = (const float*)d_in[3];
  const float* ln_g   = (const float*)d_in[4];
  const float* ln_b   = (const float*)d_in[5];
  const float* Wq  = (const float*)d_in[6];
  const float* Wk  = (const float*)d_in[7];
  const float* Wv  = (const float*)d_in[8];
  const float* Wqp = (const float*)d_in[9];
  const float* bqp = (const float*)d_in[10];
  const float* Wkp = (const float*)d_in[11];
  const float* bkp = (const float*)d_in[12];
  const float* Wvp = (const float*)d_in[13];
  const float* bvp = (const float*)d_in[14];
  const float* Wpb = (const float*)d_in[15];
  const float* hw  = (const float*)d_in[16];
  const float* Wo  = (const float*)d_in[17];
  const float* bo  = (const float*)d_in[18];
  float* out = (float*)d_out;

  float* ws = (float*)d_ws;
  // region [0, 960256): s + wcat + bcat (dead after proj GEMM), then Qa/Ka/nrm
  float* s    = ws;                  // 294912
  float* wcat = ws + 294912;         // 663552
  float* bcat = ws + 958464;         // 1792
  float* Qa   = ws;                  // 442368 (overlays s/wcat after proj GEMM)
  float* Ka   = ws + 442368;         // 442368
  float* nrm  = ws + 884736;         // 18432
  float* proj = ws + 960256;         // 1327104
  float* logits = ws + 2287360;      // 7077888 (attn in-place; part overlays later)
  float* cat  = ws + 9365248;        // 1695744
  float* fac  = ws + 11060992;       // 110592
  float* part = logits;              // 1769472 (attn dead after k_pv)

  k_layernorm<<<LSEQ, 128, 0, stream>>>(single, ln_g, ln_b, s);
  k_wcat<<<(384*PROJW+255)/256, 256, 0, stream>>>(Wq,Wk,Wv,Wqp,Wkp,Wvp,bqp,bkp,bvp,wcat,bcat);
  k_gemm<<<dim3(27,12,1), 256, 0, stream>>>(s, wcat, bcat, proj, 768, PROJW, 384, 384);
  k_frames<<<(LSEQ*192+255)/256, 256, 0, stream>>>(proj, rots, trans);
  k_prep<<<LSEQ, 256, 0, stream>>>(proj, hw, Qa, Ka, nrm);
  k_qkaug<<<dim3(12,12,12), 256, 0, stream>>>(Qa, Ka, nrm, logits);
  k_fused2<<<LSEQ, 512, 0, stream>>>(pair, Wpb, logits, fac, cat);
  k_pv<<<dim3(12, NH), 256, 0, stream>>>(logits, proj, fac, cat);
  k_outpts<<<(LSEQ*96+255)/256, 256, 0, stream>>>(rots, trans, cat);
  k_gemm<<<dim3(6,12,6), 256, 0, stream>>>(cat, Wo, nullptr, part, 768, 384, OUTD, 368);
  k_reduce<<<(LSEQ*CS+255)/256, 256, 0, stream>>>(part, bo, out);
}

// Round 4
// 423.006 us; speedup vs baseline: 2.2364x; 1.1193x over previous
//
#include <hip/hip_runtime.h>
#include <math.h>

#define LSEQ 768
#define CS   384
#define CZ   128
#define NH   12
#define OUTD 2208
#define PROJW 1728   // [q 384 | k 384 | v 384 | qp 144 | kp 144 | vp 288]
#define TIL  64
#define NT   12
#define LL2  (LSEQ*LSEQ)

__device__ __forceinline__ float waveSum(float v){
#pragma unroll
  for (int o = 32; o > 0; o >>= 1) v += __shfl_down(v, o, 64);
  return v;
}

// ---------------- LayerNorm ----------------
__global__ __launch_bounds__(128) void k_layernorm(
    const float* __restrict__ x, const float* __restrict__ g,
    const float* __restrict__ b, float* __restrict__ s){
  int i = blockIdx.x, t = threadIdx.x;
  const float* row = x + (size_t)i*CS;
  float v0 = row[t], v1 = row[t+128], v2 = row[t+256];
  float sum = v0+v1+v2;
  float sq  = v0*v0+v1*v1+v2*v2;
  float ws1 = waveSum(sum), ws2 = waveSum(sq);
  __shared__ float red[4];
  int w = t>>6, lane = t&63;
  if (lane == 0){ red[w] = ws1; red[w+2] = ws2; }
  __syncthreads();
  float mu   = (red[0]+red[1]) * (1.f/CS);
  float var  = (red[2]+red[3]) * (1.f/CS) - mu*mu;
  float rstd = rsqrtf(var + 1e-5f);
  float* o = s + (size_t)i*CS;
  o[t]     = (v0-mu)*rstd*g[t]     + b[t];
  o[t+128] = (v1-mu)*rstd*g[t+128] + b[t+128];
  o[t+256] = (v2-mu)*rstd*g[t+256] + b[t+256];
}

// ---------------- concat weights into wcat[384][1728], bcat[1728] ----------------
__global__ void k_wcat(const float* __restrict__ Wq, const float* __restrict__ Wk,
                       const float* __restrict__ Wv, const float* __restrict__ Wqp,
                       const float* __restrict__ Wkp, const float* __restrict__ Wvp,
                       const float* __restrict__ bqp, const float* __restrict__ bkp,
                       const float* __restrict__ bvp,
                       float* __restrict__ wcat, float* __restrict__ bcat){
  int idx = blockIdx.x*256 + threadIdx.x;
  if (idx < PROJW){
    float bv = 0.f;
    if (idx >= 1440)      bv = bvp[idx-1440];
    else if (idx >= 1296) bv = bkp[idx-1296];
    else if (idx >= 1152) bv = bqp[idx-1152];
    bcat[idx] = bv;
  }
  if (idx >= 384*PROJW) return;
  int r = idx / PROJW, c = idx % PROJW;
  float v;
  if (c < 384)       v = Wq[r*384 + c];
  else if (c < 768)  v = Wk[r*384 + c-384];
  else if (c < 1152) v = Wv[r*384 + c-768];
  else if (c < 1296) v = Wqp[r*144 + c-1152];
  else if (c < 1440) v = Wkp[r*144 + c-1296];
  else               v = Wvp[r*288 + c-1440];
  wcat[idx] = v;
}

// ---------------- generic tiled GEMM (64x64, BK=16) ----------------
__global__ __launch_bounds__(256) void k_gemm(
    const float* __restrict__ A, const float* __restrict__ B,
    const float* __restrict__ bias, float* __restrict__ C,
    int M, int N, int K, int kChunk){
  __shared__ float As[16][65];
  __shared__ float Bs[16][65];
  int j0 = blockIdx.x*64, i0 = blockIdx.y*64;
  int kBeg = blockIdx.z * kChunk;
  int t = threadIdx.x, tx = t & 15, ty = t >> 4;
  int arow = t >> 2, ak = (t & 3) * 4;
  int brow = t >> 4, bcol = (t & 15) * 4;
  float acc[4][4] = {};
  for (int kb = kBeg; kb < kBeg + kChunk; kb += 16){
    float4 av = *(const float4*)(A + (size_t)(i0+arow)*K + kb + ak);
    As[ak+0][arow]=av.x; As[ak+1][arow]=av.y; As[ak+2][arow]=av.z; As[ak+3][arow]=av.w;
    float4 bv = make_float4(0.f,0.f,0.f,0.f);
    if (j0 + bcol < N) bv = *(const float4*)(B + (size_t)(kb+brow)*N + j0 + bcol);
    Bs[brow][bcol+0]=bv.x; Bs[brow][bcol+1]=bv.y; Bs[brow][bcol+2]=bv.z; Bs[brow][bcol+3]=bv.w;
    __syncthreads();
#pragma unroll
    for (int kk = 0; kk < 16; ++kk){
      float a0=As[kk][ty*4+0],a1=As[kk][ty*4+1],a2=As[kk][ty*4+2],a3=As[kk][ty*4+3];
      float b0=Bs[kk][tx*4+0],b1=Bs[kk][tx*4+1],b2=Bs[kk][tx*4+2],b3=Bs[kk][tx*4+3];
      acc[0][0]+=a0*b0; acc[0][1]+=a0*b1; acc[0][2]+=a0*b2; acc[0][3]+=a0*b3;
      acc[1][0]+=a1*b0; acc[1][1]+=a1*b1; acc[1][2]+=a1*b2; acc[1][3]+=a1*b3;
      acc[2][0]+=a2*b0; acc[2][1]+=a2*b1; acc[2][2]+=a2*b2; acc[2][3]+=a2*b3;
      acc[3][0]+=a3*b0; acc[3][1]+=a3*b1; acc[3][2]+=a3*b2; acc[3][3]+=a3*b3;
    }
    __syncthreads();
  }
  bool noSplit = (gridDim.z == 1);
#pragma unroll
  for (int r = 0; r < 4; ++r){
    int i = i0 + ty*4 + r;
#pragma unroll
    for (int c = 0; c < 4; ++c){
      int j = j0 + tx*4 + c;
      if (j < N){
        float v = acc[r][c];
        if (noSplit && bias) v += bias[j];
        C[(size_t)i*N + j] = v;
      }
    }
  }
}

// ---------------- Wo GEMM: 128x128 tile, BK=8, 8x8 acc, split-K=12 ----------------
__global__ __launch_bounds__(256) void k_gemmWo(
    const float* __restrict__ A, const float* __restrict__ B, float* __restrict__ C){
  __shared__ float As[8][132];
  __shared__ float Bs[8][132];
  const int j0 = blockIdx.x*128, i0 = blockIdx.y*128;
  const int kBeg = blockIdx.z*184;
  const int t = threadIdx.x;
  const int arow = t >> 1, akq = (t & 1)*4;
  const int bk = t >> 5, bn = (t & 31)*4;
  const int tx = t & 15, ty = t >> 4;
  float acc[8][8] = {};
  for (int kb = kBeg; kb < kBeg+184; kb += 8){
    float4 av = *(const float4*)(A + (size_t)(i0+arow)*OUTD + kb + akq);
    float4 bv = *(const float4*)(B + (size_t)(kb+bk)*CS + j0 + bn);
    As[akq+0][arow]=av.x; As[akq+1][arow]=av.y; As[akq+2][arow]=av.z; As[akq+3][arow]=av.w;
    *(float4*)(&Bs[bk][bn]) = bv;
    __syncthreads();
#pragma unroll
    for (int k = 0; k < 8; ++k){
      float a[8], b[8];
      *(float4*)(a)   = *(const float4*)(&As[k][ty*8]);
      *(float4*)(a+4) = *(const float4*)(&As[k][ty*8+4]);
      *(float4*)(b)   = *(const float4*)(&Bs[k][tx*8]);
      *(float4*)(b+4) = *(const float4*)(&Bs[k][tx*8+4]);
#pragma unroll
      for (int r = 0; r < 8; ++r)
#pragma unroll
        for (int c = 0; c < 8; ++c) acc[r][c] += a[r]*b[c];
    }
    __syncthreads();
  }
  float* out = C + (size_t)blockIdx.z*LSEQ*CS;
#pragma unroll
  for (int r = 0; r < 8; ++r){
    float* o = out + (size_t)(i0+ty*8+r)*CS + j0 + tx*8;
    *(float4*)(o)   = make_float4(acc[r][0],acc[r][1],acc[r][2],acc[r][3]);
    *(float4*)(o+4) = make_float4(acc[r][4],acc[r][5],acc[r][6],acc[r][7]);
  }
}

// ---------------- apply frames in-place on proj slices ----------------
__global__ void k_frames(float* __restrict__ proj, const float* __restrict__ rots,
                         const float* __restrict__ trans){
  int idx = blockIdx.x*256 + threadIdx.x;
  if (idx >= LSEQ*192) return;
  int i = idx/192, p = idx%192;
  int off = (p < 48) ? (1152 + p*3) : ((p < 96) ? (1296 + (p-48)*3) : (1440 + (p-96)*3));
  float* pp = proj + (size_t)i*PROJW + off;
  const float* R  = rots + i*9;
  const float* tr = trans + i*3;
  float x=pp[0], y=pp[1], z=pp[2];
  pp[0] = R[0]*x + R[1]*y + R[2]*z + tr[0];
  pp[1] = R[3]*x + R[4]*y + R[5]*z + tr[1];
  pp[2] = R[6]*x + R[7]*y + R[8]*z + tr[2];
}

// ---------------- build Qa/Ka (K=44, padded 48) + norm biases ----------------
__global__ __launch_bounds__(256) void k_prep(
    const float* __restrict__ proj, const float* __restrict__ hw,
    float* __restrict__ Qa, float* __restrict__ Ka, float* __restrict__ nrm){
  int i = blockIdx.x, t = threadIdx.x;
  __shared__ float wcl[12];
  if (t < 12) wcl[t] = log1pf(__expf(hw[t]));
  __syncthreads();
  const float* prow = proj + (size_t)i*PROJW;
  const float isq = 0.17677669529663687f;
  for (int idx = t; idx < 576; idx += 256){
    int h = idx/48, d = idx%48;
    float qv = 0.f, kv = 0.f;
    if (d < 32){ qv = prow[h*32 + d]*isq; kv = prow[384 + h*32 + d]; }
    else if (d < 44){ qv = prow[1152 + h*12 + (d-32)]*wcl[h]; kv = prow[1296 + h*12 + (d-32)]; }
    Qa[((size_t)h*LSEQ + i)*48 + d] = qv;
    Ka[((size_t)h*LSEQ + i)*48 + d] = kv;
  }
  if (t < 24){
    int h = t % 12; int isK = (t >= 12) ? 1 : 0;
    const float* g = prow + (isK ? 1296 : 1152) + h*12;
    float sum = 0.f;
#pragma unroll
    for (int d = 0; d < 12; ++d) sum += g[d]*g[d];
    nrm[((size_t)(isK*12 + h))*LSEQ + i] = -0.5f*wcl[h]*sum;
  }
}

// ---------------- logits GEMM: logits[h][i][j] = Qa_i . Ka_j + nq[i] + nk[j] ----------------
__global__ __launch_bounds__(256) void k_qkaug(
    const float* __restrict__ Qa, const float* __restrict__ Ka,
    const float* __restrict__ nrm, float* __restrict__ logits){
  int j0 = blockIdx.x*64, i0 = blockIdx.y*64, h = blockIdx.z;
  __shared__ float Qs[64*49], Ks[64*49];
  __shared__ float nq[64], nk[64];
  int t = threadIdx.x;
  for (int idx = t; idx < 768; idx += 256){
    int row = idx/12, c4 = (idx%12)*4;
    float4 qv = *(const float4*)(Qa + ((size_t)h*LSEQ + i0+row)*48 + c4);
    Qs[row*49+c4]=qv.x; Qs[row*49+c4+1]=qv.y; Qs[row*49+c4+2]=qv.z; Qs[row*49+c4+3]=qv.w;
    float4 kv = *(const float4*)(Ka + ((size_t)h*LSEQ + j0+row)*48 + c4);
    Ks[row*49+c4]=kv.x; Ks[row*49+c4+1]=kv.y; Ks[row*49+c4+2]=kv.z; Ks[row*49+c4+3]=kv.w;
  }
  if (t < 64) nq[t] = nrm[(size_t)h*LSEQ + i0 + t];
  else if (t < 128) nk[t-64] = nrm[(size_t)(12+h)*LSEQ + j0 + (t-64)];
  __syncthreads();
  int tx = t & 15, ty = t >> 4;
  float acc[4][4] = {};
#pragma unroll 4
  for (int k = 0; k < 44; ++k){
    float a0=Qs[(ty*4+0)*49+k], a1=Qs[(ty*4+1)*49+k], a2=Qs[(ty*4+2)*49+k], a3=Qs[(ty*4+3)*49+k];
    float b0=Ks[(tx*4+0)*49+k], b1=Ks[(tx*4+1)*49+k], b2=Ks[(tx*4+2)*49+k], b3=Ks[(tx*4+3)*49+k];
    acc[0][0]+=a0*b0; acc[0][1]+=a0*b1; acc[0][2]+=a0*b2; acc[0][3]+=a0*b3;
    acc[1][0]+=a1*b0; acc[1][1]+=a1*b1; acc[1][2]+=a1*b2; acc[1][3]+=a1*b3;
    acc[2][0]+=a2*b0; acc[2][1]+=a2*b1; acc[2][2]+=a2*b2; acc[2][3]+=a2*b3;
    acc[3][0]+=a3*b0; acc[3][1]+=a3*b1; acc[3][2]+=a3*b2; acc[3][3]+=a3*b3;
  }
  float nqa[4] = {nq[ty*4], nq[ty*4+1], nq[ty*4+2], nq[ty*4+3]};
  float nk0=nk[tx*4], nk1=nk[tx*4+1], nk2=nk[tx*4+2], nk3=nk[tx*4+3];
#pragma unroll
  for (int r = 0; r < 4; ++r){
    float4 o = make_float4(acc[r][0]+nqa[r]+nk0, acc[r][1]+nqa[r]+nk1,
                           acc[r][2]+nqa[r]+nk2, acc[r][3]+nqa[r]+nk3);
    *(float4*)(logits + ((size_t)h*LSEQ + i0+ty*4+r)*LSEQ + j0 + tx*4) = o;
  }
}

// ---------------- fused v3: pairbias + online softmax + out_pair; block per i ----------------
__global__ __launch_bounds__(512) void k_fused2(
    const float* __restrict__ pair, const float* __restrict__ Wpb,
    float* __restrict__ attn,   // logits in -> unnormalized probs out (in-place)
    float* __restrict__ fac,    // [768][12][12] per-tile correction incl 1/l
    float* __restrict__ cat){
  const int i = blockIdx.x, t = threadIdx.x;
  __shared__ __align__(16) float pairT[64*132];   // [j][c], also epilogue scratch
  __shared__ __align__(16) float wpbL[12*132];    // [h][c]
  __shared__ __align__(16) float Sb[12*68];       // pairbias tile
  __shared__ __align__(16) float S[12*68];        // P tile
  __shared__ float m_run[12], l_run[12], scb[12];
  __shared__ float mh[12][12];                    // [tile][h]

  // fill wpbL[h][c] = Wpb[c][h]
  for (int idx = t; idx < 1536; idx += 512){
    int h = idx >> 7, c = idx & 127;
    wpbL[h*132 + c] = Wpb[c*12 + h];
  }
  if (t < 12){ m_run[t] = -1e30f; l_run[t] = 0.f; }

  // --- phase A ids (pairbias): 16 ch-groups x 16 row-groups x 2 head-halves ---
  const int cg = t & 15;          // ch quads: cg*4 and 64+cg*4
  const int rg = (t >> 4) & 15;   // rows rg*4 .. rg*4+3
  const int hs = t >> 8;          // heads hs*6 .. hs*6+5
  // --- phase C ids (out_pair): 32 ch-quads x 4 head-groups x 4 j-chunks ---
  const int cq = t & 31;
  const int hg = (t >> 5) & 3;
  const int js = t >> 7;
  // --- softmax ids (t<384) ---
  const int sh = 2*(t>>6) + ((t>>5)&1), sjj = t & 31;
  float* lrow = attn + (size_t)sh*LL2 + (size_t)i*LSEQ + sjj;

  const float* pbase = pair + (size_t)i*LSEQ*CZ;
  // prefetch tile 0 pair rows
  float4 pf[8];
#pragma unroll
  for (int r = 0; r < 4; ++r){
    const float* pr = pbase + (size_t)(rg*4+r)*CZ;
    pf[r*2+0] = *(const float4*)(pr + cg*4);
    pf[r*2+1] = *(const float4*)(pr + 64 + cg*4);
  }
  float gl0 = 0.f, gl1 = 0.f;
  if (t < 384){ gl0 = lrow[0]; gl1 = lrow[32]; }
  float accP[4][3] = {};
  __syncthreads();

  // hoist weights into registers (constant across tiles)
  float4 w0[6], w1[6];
#pragma unroll
  for (int e = 0; e < 6; ++e){
    w0[e] = *(const float4*)(wpbL + (hs*6+e)*132 + cg*4);
    w1[e] = *(const float4*)(wpbL + (hs*6+e)*132 + 64 + cg*4);
  }

  for (int jt = 0; jt < NT; ++jt){
    const int j0 = jt*TIL;
    // ================= A: pairbias + stash =================
    {
      float accB[4][6];
#pragma unroll
      for (int r = 0; r < 4; ++r){
        float4 a = pf[r*2], b = pf[r*2+1];
#pragma unroll
        for (int e = 0; e < 6; ++e){
          accB[r][e] = a.x*w0[e].x + a.y*w0[e].y + a.z*w0[e].z + a.w*w0[e].w
                     + b.x*w1[e].x + b.y*w1[e].y + b.z*w1[e].z + b.w*w1[e].w;
        }
      }
#pragma unroll
      for (int r = 0; r < 4; ++r)
#pragma unroll
        for (int e = 0; e < 6; ++e){
          float v = accB[r][e];
          v += __shfl_xor(v, 1); v += __shfl_xor(v, 2);
          v += __shfl_xor(v, 4); v += __shfl_xor(v, 8);
          accB[r][e] = v;
        }
      if (cg == 0){
#pragma unroll
        for (int r = 0; r < 4; ++r)
#pragma unroll
          for (int e = 0; e < 6; ++e)
            Sb[(hs*6+e)*68 + rg*4 + r] = accB[r][e];
      }
      if (hs == 0){
#pragma unroll
        for (int r = 0; r < 4; ++r){
          *(float4*)(pairT + (rg*4+r)*132 + cg*4)      = pf[r*2+0];
          *(float4*)(pairT + (rg*4+r)*132 + 64 + cg*4) = pf[r*2+1];
        }
      }
    }
    __syncthreads();
    // ================= B: prefetch + online softmax =================
    if (jt < NT-1){
#pragma unroll
      for (int r = 0; r < 4; ++r){
        const float* pr = pbase + (size_t)(j0+64 + rg*4+r)*CZ;
        pf[r*2+0] = *(const float4*)(pr + cg*4);
        pf[r*2+1] = *(const float4*)(pr + 64 + cg*4);
      }
    }
    float ngl0 = 0.f, ngl1 = 0.f;
    if (t < 384 && jt < NT-1){ ngl0 = lrow[j0+64]; ngl1 = lrow[j0+96]; }
    if (t < 384){
      float s0 = gl0 + Sb[sh*68 + sjj];
      float s1 = gl1 + Sb[sh*68 + sjj + 32];
      float mt = fmaxf(s0, s1);
#pragma unroll
      for (int m = 16; m > 0; m >>= 1) mt = fmaxf(mt, __shfl_xor(mt, m));
      float mo = m_run[sh], mn = fmaxf(mo, mt);
      float p0 = __expf(s0 - mn), p1 = __expf(s1 - mn);
      float ts = p0 + p1;
#pragma unroll
      for (int m = 16; m > 0; m >>= 1) ts += __shfl_xor(ts, m);
      S[sh*68 + sjj] = p0; S[sh*68 + sjj + 32] = p1;
      lrow[j0] = p0; lrow[j0 + 32] = p1;
      if (sjj == 0){
        float sc = __expf(mo - mn);
        scb[sh] = sc; l_run[sh] = l_run[sh]*sc + ts; m_run[sh] = mn;
        mh[jt][sh] = mn;
      }
      gl0 = ngl0; gl1 = ngl1;
    }
    __syncthreads();
    // ================= C: out_pair accumulate =================
    {
      float f0 = scb[hg*3+0], f1 = scb[hg*3+1], f2 = scb[hg*3+2];
#pragma unroll
      for (int ci = 0; ci < 4; ++ci){
        accP[ci][0] *= f0; accP[ci][1] *= f1; accP[ci][2] *= f2;
      }
#pragma unroll
      for (int q = 0; q < 4; ++q){
        const int jb = js*16 + q*4;
        float4 ps0 = *(const float4*)(S + (hg*3+0)*68 + jb);
        float4 ps1 = *(const float4*)(S + (hg*3+1)*68 + jb);
        float4 ps2 = *(const float4*)(S + (hg*3+2)*68 + jb);
#pragma unroll
        for (int r = 0; r < 4; ++r){
          float4 pv = *(const float4*)(pairT + (size_t)(jb+r)*132 + cq*4);
          float p0 = (&ps0.x)[r], p1 = (&ps1.x)[r], p2 = (&ps2.x)[r];
          accP[0][0] += pv.x*p0; accP[1][0] += pv.y*p0; accP[2][0] += pv.z*p0; accP[3][0] += pv.w*p0;
          accP[0][1] += pv.x*p1; accP[1][1] += pv.y*p1; accP[2][1] += pv.z*p1; accP[3][1] += pv.w*p1;
          accP[0][2] += pv.x*p2; accP[1][2] += pv.y*p2; accP[2][2] += pv.z*p2; accP[3][2] += pv.w*p2;
        }
      }
    }
    __syncthreads();
  }
  // ================= epilogue =================
  // reduce accP over js via LDS (reuse pairT as red[4][1536])
  float* red = pairT;
#pragma unroll
  for (int e = 0; e < 3; ++e)
#pragma unroll
    for (int ci = 0; ci < 4; ++ci)
      red[js*1536 + (hg*3+e)*128 + cq*4 + ci] = accP[ci][e];
  if (t < 144){
    int h = t/12, tile = t%12;
    fac[(size_t)i*144 + t] = __expf(mh[tile][h] - m_run[h]) / l_run[h];
  }
  __syncthreads();
  float* crow = cat + (size_t)i*OUTD + 672;
  for (int o = t; o < 1536; o += 512){
    float v = red[o] + red[1536+o] + red[3072+o] + red[4608+o];
    crow[o] = v / l_run[o >> 7];
  }
}

// ---------------- PV GEMM: cat[v|pts_g] = (attn*fac) @ [v|vg] ----------------
__global__ __launch_bounds__(256) void k_pv(
    const float* __restrict__ attn, const float* __restrict__ proj,
    const float* __restrict__ fac, float* __restrict__ cat){
  int h = blockIdx.y, i0 = blockIdx.x*64;
  __shared__ float As[32][65];
  __shared__ float Bs[32][57];
  __shared__ float facs[64][12];
  int t = threadIdx.x, tx = t & 15, ty = t >> 4;
  for (int idx = t; idx < 768; idx += 256){
    int row = idx/12, tile = idx%12;
    facs[row][tile] = fac[(size_t)(i0+row)*144 + h*12 + tile];
  }
  float acc[4][4] = {};
  for (int kb = 0; kb < LSEQ; kb += 32){
    __syncthreads();
    for (int idx = t; idx < 512; idx += 256){
      int row = idx >> 3, k4 = (idx & 7)*4;
      float4 av = *(const float4*)(attn + ((size_t)h*LSEQ + i0 + row)*LSEQ + kb + k4);
      float fm = facs[row][kb>>6];
      As[k4+0][row]=av.x*fm; As[k4+1][row]=av.y*fm; As[k4+2][row]=av.z*fm; As[k4+3][row]=av.w*fm;
    }
    for (int idx = t; idx < 32*56; idx += 256){
      int kk = idx/56, n = idx%56;
      const float* prow = proj + (size_t)(kb+kk)*PROJW;
      Bs[kk][n] = (n < 32) ? prow[768 + h*32 + n] : prow[1440 + h*24 + (n-32)];
    }
    __syncthreads();
#pragma unroll
    for (int kk = 0; kk < 32; ++kk){
      float a0=As[kk][ty*4+0],a1=As[kk][ty*4+1],a2=As[kk][ty*4+2],a3=As[kk][ty*4+3];
      float b0=Bs[kk][tx*4+0],b1=Bs[kk][tx*4+1],b2=Bs[kk][tx*4+2],b3=Bs[kk][tx*4+3];
      acc[0][0]+=a0*b0; acc[0][1]+=a0*b1; acc[0][2]+=a0*b2; acc[0][3]+=a0*b3;
      acc[1][0]+=a1*b0; acc[1][1]+=a1*b1; acc[1][2]+=a1*b2; acc[1][3]+=a1*b3;
      acc[2][0]+=a2*b0; acc[2][1]+=a2*b1; acc[2][2]+=a2*b2; acc[2][3]+=a2*b3;
      acc[3][0]+=a3*b0; acc[3][1]+=a3*b1; acc[3][2]+=a3*b2; acc[3][3]+=a3*b3;
    }
  }
#pragma unroll
  for (int r = 0; r < 4; ++r){
    int i = i0 + ty*4 + r;
#pragma unroll
    for (int c = 0; c < 4; ++c){
      int n = tx*4 + c;
      float val = acc[r][c];
      if (n < 32)      cat[(size_t)i*OUTD + h*32 + n] = val;
      else if (n < 56) cat[(size_t)i*OUTD + 384 + h*24 + (n-32)] = val;
    }
  }
}

// ---------------- rotate output points back to local frame ----------------
__global__ void k_outpts(const float* __restrict__ rots, const float* __restrict__ trans,
                         float* __restrict__ cat){
  int idx = blockIdx.x*256 + threadIdx.x;
  if (idx >= LSEQ*96) return;
  int i = idx/96, n = idx%96;
  float* p = cat + (size_t)i*OUTD + 384 + n*3;
  const float* R  = rots + i*9;
  const float* tr = trans + i*3;
  float x = p[0]-tr[0], y = p[1]-tr[1], z = p[2]-tr[2];
  p[0] = R[0]*x + R[3]*y + R[6]*z;
  p[1] = R[1]*x + R[4]*y + R[7]*z;
  p[2] = R[2]*x + R[5]*y + R[8]*z;
}

// ---------------- split-K reduce + bias ----------------
__global__ __launch_bounds__(256) void k_reduce(
    const float* __restrict__ part, const float* __restrict__ bias,
    float* __restrict__ out){
  int idx = blockIdx.x*256 + threadIdx.x;
  if (idx >= LSEQ*CS) return;
  float v = bias[idx % CS];
#pragma unroll
  for (int z = 0; z < 12; ++z) v += part[(size_t)z*LSEQ*CS + idx];
  out[idx] = v;
}

extern "C" void kernel_launch(void* const* d_in, const int* in_sizes, int n_in,
                              void* d_out, int out_size, void* d_ws, size_t ws_size,
                              hipStream_t stream){
  const float* single = (const float*)d_in[0];
  const float* pair   = (const float*)d_in[1];
  const float* rots   = (const float*)d_in[2];
  const float* trans  = (const float*)d_in[3];
  const float* ln_g   = (const float*)d_in[4];
  const float* ln_b   = (const float*)d_in[5];
  const float* Wq  = (const float*)d_in[6];
  const float* Wk  = (const float*)d_in[7];
  const float* Wv  = (const float*)d_in[8];
  const float* Wqp = (const float*)d_in[9];
  const float* bqp = (const float*)d_in[10];
  const float* Wkp = (const float*)d_in[11];
  const float* bkp = (const float*)d_in[12];
  const float* Wvp = (const float*)d_in[13];
  const float* bvp = (const float*)d_in[14];
  const float* Wpb = (const float*)d_in[15];
  const float* hw  = (const float*)d_in[16];
  const float* Wo  = (const float*)d_in[17];
  const float* bo  = (const float*)d_in[18];
  float* out = (float*)d_out;

  float* ws = (float*)d_ws;
  float* s    = ws;                  // 294912
  float* wcat = ws + 294912;         // 663552
  float* bcat = ws + 958464;         // 1792
  float* Qa   = ws;                  // overlays s/wcat after proj GEMM
  float* Ka   = ws + 442368;
  float* nrm  = ws + 884736;
  float* proj = ws + 960256;         // 1327104
  float* logits = ws + 2287360;      // 7077888 (attn in-place; part overlays)
  float* cat  = ws + 9365248;        // 1695744
  float* fac  = ws + 11060992;       // 110592
  float* part = logits;              // 12*294912 = 3538944 <= 7077888

  k_layernorm<<<LSEQ, 128, 0, stream>>>(single, ln_g, ln_b, s);
  k_wcat<<<(384*PROJW+255)/256, 256, 0, stream>>>(Wq,Wk,Wv,Wqp,Wkp,Wvp,bqp,bkp,bvp,wcat,bcat);
  k_gemm<<<dim3(27,12,1), 256, 0, stream>>>(s, wcat, bcat, proj, 768, PROJW, 384, 384);
  k_frames<<<(LSEQ*192+255)/256, 256, 0, stream>>>(proj, rots, trans);
  k_prep<<<LSEQ, 256, 0, stream>>>(proj, hw, Qa, Ka, nrm);
  k_qkaug<<<dim3(12,12,12), 256, 0, stream>>>(Qa, Ka, nrm, logits);
  k_fused2<<<LSEQ, 512, 0, stream>>>(pair, Wpb, logits, fac, cat);
  k_pv<<<dim3(12, NH), 256, 0, stream>>>(logits, proj, fac, cat);
  k_outpts<<<(LSEQ*96+255)/256, 256, 0, stream>>>(rots, trans, cat);
  k_gemmWo<<<dim3(3,6,12), 256, 0, stream>>>(cat, Wo, part);
  k_reduce<<<(LSEQ*CS+255)/256, 256, 0, stream>>>(part, bo, out);
}